// Round 1
// baseline (674.493 us; speedup 1.0000x reference)
//
#include <hip/hip_runtime.h>

typedef unsigned short u16;
typedef __attribute__((ext_vector_type(8))) short bf16x8;   // 8 bf16 = 4 VGPRs
typedef __attribute__((ext_vector_type(4))) float f32x4;

#define EMBED 1024
#define FFDIM 4096
#define SEQ   2048
#define NTOK  8192

__device__ __forceinline__ u16 f2bf(float f) {              // RNE fp32->bf16
  union { float f; unsigned int u; } c; c.f = f;
  unsigned int r = ((c.u >> 16) & 1u) + 0x7fffu;
  return (u16)((c.u + r) >> 16);
}

__device__ __forceinline__ void gload16(const u16* g, u16* l) {
  __builtin_amdgcn_global_load_lds((const __attribute__((address_space(1))) void*)g,
                                   (__attribute__((address_space(3))) void*)l, 16, 0, 0);
}

// ---------------- fp32 [K][N] -> bf16 [N][K] (B^T layout for GEMM) -----------
__global__ __launch_bounds__(256) void wtrans(const float* __restrict__ W,
                                              u16* __restrict__ Wt, int K, int N) {
  __shared__ float tile[32][33];
  const int tx = threadIdx.x & 31, ty = threadIdx.x >> 5;
  const int n0 = blockIdx.x << 5, k0 = blockIdx.y << 5;
#pragma unroll
  for (int r = 0; r < 32; r += 8)
    tile[ty + r][tx] = W[(size_t)(k0 + ty + r) * N + n0 + tx];
  __syncthreads();
#pragma unroll
  for (int r = 0; r < 32; r += 8)
    Wt[(size_t)(n0 + ty + r) * K + k0 + tx] = f2bf(tile[tx][ty + r]);
}

// ---------------- V part of qkv [token][2048+h*64+d] -> Vt [bh*64+d][t] ------
__global__ __launch_bounds__(256) void vtrans(const u16* __restrict__ qkv,
                                              u16* __restrict__ Vt) {
  __shared__ u16 tile[32][33];
  const int tx = threadIdx.x & 31, ty = threadIdx.x >> 5;
  const int t0 = blockIdx.x << 5;
  const int rg0 = blockIdx.y << 5;            // global V row = bh*64 + d
  const int bh = rg0 >> 6, d0 = rg0 & 63;
  const int b = bh >> 4, h = bh & 15;
#pragma unroll
  for (int r = 0; r < 32; r += 8)
    tile[ty + r][tx] = qkv[(size_t)(b * SEQ + t0 + ty + r) * 3072 + 2048 + h * 64 + d0 + tx];
  __syncthreads();
#pragma unroll
  for (int r = 0; r < 32; r += 8)
    Vt[(size_t)(rg0 + ty + r) * SEQ + t0 + tx] = tile[tx][ty + r];
}

// ---------------- LayerNorm fp32 in -> bf16 out ------------------------------
__global__ __launch_bounds__(256) void ln_kernel(const float* __restrict__ xin,
                                                 const float* __restrict__ gamma,
                                                 const float* __restrict__ beta,
                                                 u16* __restrict__ out) {
  const int row = blockIdx.x, tid = threadIdx.x;
  const float4 v = reinterpret_cast<const float4*>(xin + (size_t)row * EMBED)[tid];
  float s  = v.x + v.y + v.z + v.w;
  float ss = v.x * v.x + v.y * v.y + v.z * v.z + v.w * v.w;
#pragma unroll
  for (int m = 1; m < 64; m <<= 1) { s += __shfl_xor(s, m); ss += __shfl_xor(ss, m); }
  __shared__ float red[8];
  if ((tid & 63) == 0) { red[tid >> 6] = s; red[4 + (tid >> 6)] = ss; }
  __syncthreads();
  s  = red[0] + red[1] + red[2] + red[3];
  ss = red[4] + red[5] + red[6] + red[7];
  const float mean = s * (1.0f / EMBED);
  const float var  = ss * (1.0f / EMBED) - mean * mean;
  const float rstd = rsqrtf(var + 1e-5f);
  const float4 g  = reinterpret_cast<const float4*>(gamma)[tid];
  const float4 bb = reinterpret_cast<const float4*>(beta)[tid];
  ushort4 o;
  o.x = f2bf((v.x - mean) * rstd * g.x + bb.x);
  o.y = f2bf((v.y - mean) * rstd * g.y + bb.y);
  o.z = f2bf((v.z - mean) * rstd * g.z + bb.z);
  o.w = f2bf((v.w - mean) * rstd * g.w + bb.w);
  reinterpret_cast<ushort4*>(out + (size_t)row * EMBED)[tid] = o;
}

// ---------------- bf16 GEMM, A [M][K] x Bt [N][K] -> C [M][N] ----------------
// EPI 0: store bf16 | 1: +bias +res -> fp32 | 2: +bias, GELU -> bf16
template <int EPI>
__global__ __launch_bounds__(256) void gemm_bt(const u16* __restrict__ A,
                                               const u16* __restrict__ Bt,
                                               void* __restrict__ Cv,
                                               const float* __restrict__ bias,
                                               const float* __restrict__ res,
                                               int M, int N, int K) {
  __shared__ __align__(16) u16 As[128 * 64];   // [row][k], XOR-swizzled
  __shared__ __align__(16) u16 Bs[128 * 64];   // [col][k], XOR-swizzled
  const int tid = threadIdx.x;
  const int lane = tid & 63, wid = tid >> 6;
  const int l4 = lane >> 4, l15 = lane & 15;
  const int wr = wid >> 1, wc = wid & 1;
  const int brow = blockIdx.y << 7, bcol = blockIdx.x << 7;

  const f32x4 z4 = {0.f, 0.f, 0.f, 0.f};
  f32x4 acc[4][4];
#pragma unroll
  for (int m = 0; m < 4; ++m)
#pragma unroll
    for (int n = 0; n < 4; ++n) acc[m][n] = z4;

  // staging: thread tid supplies LDS linear slot (p*256+tid)*16B
  // -> tile row p*32 + tid/8, phys kbyte (tid&7)*16; source kbyte pre-swizzled
  const int srow = tid >> 3;
  const int srck = ((tid & 7) << 4) ^ ((srow & 7) << 4);
  const u16* gA = A  + (size_t)(brow + srow) * K + (srck >> 1);
  const u16* gB = Bt + (size_t)(bcol + srow) * K + (srck >> 1);

  const int nk = K >> 6;
  for (int kt = 0; kt < nk; ++kt) {
    __syncthreads();
#pragma unroll
    for (int p = 0; p < 4; ++p) {
      gload16(gA + (size_t)p * 32 * K, &As[(p * 256 + wid * 64) * 8]);
      gload16(gB + (size_t)p * 32 * K, &Bs[(p * 256 + wid * 64) * 8]);
    }
    gA += 64; gB += 64;
    __syncthreads();
#pragma unroll
    for (int ks = 0; ks < 2; ++ks) {
      bf16x8 af[4], bfr[4];
      const int kk = ks * 32 + (l4 << 3);
#pragma unroll
      for (int m = 0; m < 4; ++m) {
        const int r = wr * 64 + m * 16 + l15;
        af[m] = *(const bf16x8*)&As[r * 64 + (kk ^ ((r & 7) << 3))];
      }
#pragma unroll
      for (int n = 0; n < 4; ++n) {
        const int r = wc * 64 + n * 16 + l15;
        bfr[n] = *(const bf16x8*)&Bs[r * 64 + (kk ^ ((r & 7) << 3))];
      }
#pragma unroll
      for (int m = 0; m < 4; ++m)
#pragma unroll
        for (int n = 0; n < 4; ++n)
          acc[m][n] = __builtin_amdgcn_mfma_f32_16x16x32_bf16(af[m], bfr[n], acc[m][n], 0, 0, 0);
    }
  }

  // C/D layout (verified): col = lane&15, row = (lane>>4)*4 + reg
  const int rowb = brow + wr * 64 + (l4 << 2);
  const int colb = bcol + wc * 64 + l15;
#pragma unroll
  for (int n = 0; n < 4; ++n) {
    const int col = colb + n * 16;
    float bv = 0.f;
    if (EPI != 0) bv = bias[col];
#pragma unroll
    for (int m = 0; m < 4; ++m) {
#pragma unroll
      for (int j = 0; j < 4; ++j) {
        const int row = rowb + m * 16 + j;
        const float v = acc[m][n][j];
        if (EPI == 0) {
          ((u16*)Cv)[(size_t)row * N + col] = f2bf(v);
        } else if (EPI == 1) {
          ((float*)Cv)[(size_t)row * N + col] = v + bv + res[(size_t)row * N + col];
        } else {
          const float t = v + bv;
          const float gl = 0.5f * t * (1.0f + erff(t * 0.70710678118654752f));
          ((u16*)Cv)[(size_t)row * N + col] = f2bf(gl);
        }
      }
    }
  }
}

// ---------------- causal flash attention, 4 waves x 16 q-rows, KVBLK=32 ------
__global__ __launch_bounds__(256) void attn_fwd(const u16* __restrict__ qkv,
                                                const u16* __restrict__ Vt,
                                                u16* __restrict__ attn) {
  __shared__ __align__(16) u16 Ks[32 * 72];       // [kv][d], pad 8
  __shared__ __align__(16) u16 Vs[64 * 40];       // [d][kv], pad 8
  __shared__ __align__(16) u16 Ps[4 * 16 * 40];   // per-wave P, pad 8
  const int tid = threadIdx.x, lane = tid & 63, wid = tid >> 6;
  const int l4 = lane >> 4, l15 = lane & 15;
  const int qb = ((int)gridDim.x - 1 - (int)blockIdx.x) << 6;  // heavy blocks first
  const int bh = blockIdx.y, b = bh >> 4, h = bh & 15;
  const size_t bt0 = (size_t)b * SEQ;

  // Q fragments in registers (rows qb + wid*16 + l15)
  const u16* qptr = qkv + (bt0 + qb + wid * 16 + l15) * 3072 + h * 64 + (l4 << 3);
  const bf16x8 aq0 = *(const bf16x8*)qptr;
  const bf16x8 aq1 = *(const bf16x8*)(qptr + 32);

  const f32x4 z4 = {0.f, 0.f, 0.f, 0.f};
  f32x4 o[4]; o[0] = z4; o[1] = z4; o[2] = z4; o[3] = z4;
  float mrun[4], lrun[4];
#pragma unroll
  for (int j = 0; j < 4; ++j) { mrun[j] = -1e30f; lrun[j] = 0.f; }

  const int kr = tid >> 3, kc = (tid & 7) << 3;   // K staging: 32 rows x 8 chunks
  const int vd = tid >> 2, vc = (tid & 3) << 3;   // V staging: 64 rows x 4 chunks
  const u16* kbase = qkv + bt0 * 3072 + 1024 + h * 64;
  const u16* vbase = Vt + (size_t)bh * 64 * SEQ;
  const int wqhi = qb + wid * 16 + 15;
  const int rowq0 = qb + wid * 16 + l4 * 4;

  for (int j0 = 0; j0 < qb + 64; j0 += 32) {
    __syncthreads();
    *(bf16x8*)&Ks[kr * 72 + kc] = *(const bf16x8*)(kbase + (size_t)(j0 + kr) * 3072 + kc);
    *(bf16x8*)&Vs[vd * 40 + vc] = *(const bf16x8*)(vbase + (size_t)vd * SEQ + j0 + vc);
    __syncthreads();
    if (j0 > wqhi) continue;                       // wave fully masked

    f32x4 s0 = z4, s1 = z4;
    {
      const bf16x8 bk00 = *(const bf16x8*)&Ks[l15 * 72 + (l4 << 3)];
      const bf16x8 bk01 = *(const bf16x8*)&Ks[l15 * 72 + 32 + (l4 << 3)];
      s0 = __builtin_amdgcn_mfma_f32_16x16x32_bf16(aq0, bk00, s0, 0, 0, 0);
      s0 = __builtin_amdgcn_mfma_f32_16x16x32_bf16(aq1, bk01, s0, 0, 0, 0);
      const bf16x8 bk10 = *(const bf16x8*)&Ks[(16 + l15) * 72 + (l4 << 3)];
      const bf16x8 bk11 = *(const bf16x8*)&Ks[(16 + l15) * 72 + 32 + (l4 << 3)];
      s1 = __builtin_amdgcn_mfma_f32_16x16x32_bf16(aq0, bk10, s1, 0, 0, 0);
      s1 = __builtin_amdgcn_mfma_f32_16x16x32_bf16(aq1, bk11, s1, 0, 0, 0);
    }
    float p0[4], p1[4];
#pragma unroll
    for (int j = 0; j < 4; ++j) {
      p0[j] = (j0 + l15      > rowq0 + j) ? -1e30f : s0[j] * 0.125f;
      p1[j] = (j0 + 16 + l15 > rowq0 + j) ? -1e30f : s1[j] * 0.125f;
    }
#pragma unroll
    for (int j = 0; j < 4; ++j) {
      float mt = fmaxf(p0[j], p1[j]);
#pragma unroll
      for (int mm = 1; mm < 16; mm <<= 1) mt = fmaxf(mt, __shfl_xor(mt, mm));
      const float mn = fmaxf(mrun[j], mt);
      const float sc = __expf(mrun[j] - mn);
      mrun[j] = mn;
      p0[j] = __expf(p0[j] - mn);
      p1[j] = __expf(p1[j] - mn);
      float ls = p0[j] + p1[j];
#pragma unroll
      for (int mm = 1; mm < 16; mm <<= 1) ls += __shfl_xor(ls, mm);
      lrun[j] = lrun[j] * sc + ls;
      o[0][j] *= sc; o[1][j] *= sc; o[2][j] *= sc; o[3][j] *= sc;
    }
#pragma unroll
    for (int j = 0; j < 4; ++j) {
      Ps[wid * 640 + (l4 * 4 + j) * 40 + l15]      = f2bf(p0[j]);
      Ps[wid * 640 + (l4 * 4 + j) * 40 + 16 + l15] = f2bf(p1[j]);
    }
    const bf16x8 ap = *(const bf16x8*)&Ps[wid * 640 + l15 * 40 + (l4 << 3)];
#pragma unroll
    for (int dt = 0; dt < 4; ++dt) {
      const bf16x8 bv = *(const bf16x8*)&Vs[(dt * 16 + l15) * 40 + (l4 << 3)];
      o[dt] = __builtin_amdgcn_mfma_f32_16x16x32_bf16(ap, bv, o[dt], 0, 0, 0);
    }
  }

  const size_t rowt = bt0 + qb + wid * 16 + l4 * 4;
#pragma unroll
  for (int dt = 0; dt < 4; ++dt) {
    const int col = h * 64 + dt * 16 + l15;
#pragma unroll
    for (int j = 0; j < 4; ++j)
      attn[(rowt + j) * EMBED + col] = f2bf(o[dt][j] / lrun[j]);
  }
}

// ---------------- driver ------------------------------------------------------
extern "C" void kernel_launch(void* const* d_in, const int* in_sizes, int n_in,
                              void* d_out, int out_size, void* d_ws, size_t ws_size,
                              hipStream_t stream) {
  const float* x   = (const float*)d_in[0];
  const float* Wq  = (const float*)d_in[1];
  const float* Wk  = (const float*)d_in[2];
  const float* Wv  = (const float*)d_in[3];
  const float* Wo  = (const float*)d_in[4];
  const float* bo  = (const float*)d_in[5];
  const float* W1  = (const float*)d_in[6];
  const float* b1  = (const float*)d_in[7];
  const float* W2  = (const float*)d_in[8];
  const float* b2  = (const float*)d_in[9];
  const float* g1  = (const float*)d_in[10];
  const float* be1 = (const float*)d_in[11];
  const float* g2  = (const float*)d_in[12];
  const float* be2 = (const float*)d_in[13];

  char* ws = (char*)d_ws;                       // total 159,383,552 B used
  u16* wqkv_t = (u16*)(ws + 0);                 // [3072][1024] bf16   6 MB
  u16* wo_t   = (u16*)(ws + 6291456);           // [1024][1024]        2 MB
  u16* w1_t   = (u16*)(ws + 8388608);           // [4096][1024]        8 MB
  u16* w2_t   = (u16*)(ws + 16777216);          // [1024][4096]        8 MB
  u16* hbuf   = (u16*)(ws + 25165824);          // LN out, reused     16 MB
  u16* qkv    = (u16*)(ws + 41943040);          // [8192][3072]       48 MB
  u16* ff1    = (u16*)(ws + 41943040);          // overlaps qkv+Vt    64 MB
  u16* vt     = (u16*)(ws + 92274688);          // [64*64][2048]      16 MB
  u16* attnb  = (u16*)(ws + 109051904);         // [8192][1024]       16 MB
  float* x2   = (float*)(ws + 125829120);       // fp32 residual      32 MB
  float* outp = (float*)d_out;

  dim3 blk(256);
  wtrans<<<dim3(32, 32),  blk, 0, stream>>>(Wq, wqkv_t,               1024, 1024);
  wtrans<<<dim3(32, 32),  blk, 0, stream>>>(Wk, wqkv_t + 1024 * 1024, 1024, 1024);
  wtrans<<<dim3(32, 32),  blk, 0, stream>>>(Wv, wqkv_t + 2048 * 1024, 1024, 1024);
  wtrans<<<dim3(32, 32),  blk, 0, stream>>>(Wo, wo_t,                 1024, 1024);
  wtrans<<<dim3(128, 32), blk, 0, stream>>>(W1, w1_t,                 1024, 4096);
  wtrans<<<dim3(32, 128), blk, 0, stream>>>(W2, w2_t,                 4096, 1024);

  ln_kernel<<<dim3(8192), blk, 0, stream>>>(x, g1, be1, hbuf);
  gemm_bt<0><<<dim3(24, 64), blk, 0, stream>>>(hbuf, wqkv_t, qkv, nullptr, nullptr,
                                               8192, 3072, 1024);
  vtrans<<<dim3(64, 128), blk, 0, stream>>>(qkv, vt);
  attn_fwd<<<dim3(32, 64), blk, 0, stream>>>(qkv, vt, attnb);
  gemm_bt<1><<<dim3(8, 64), blk, 0, stream>>>(attnb, wo_t, x2, bo, x,
                                              8192, 1024, 1024);
  ln_kernel<<<dim3(8192), blk, 0, stream>>>(x2, g2, be2, hbuf);
  gemm_bt<2><<<dim3(32, 64), blk, 0, stream>>>(hbuf, w1_t, ff1, b1, nullptr,
                                               8192, 4096, 1024);
  gemm_bt<1><<<dim3(8, 64), blk, 0, stream>>>(ff1, w2_t, outp, b2, x2,
                                              8192, 1024, 4096);
}